// Round 1
// baseline (1382.726 us; speedup 1.0000x reference)
//
#include <hip/hip_runtime.h>
#include <hip/hip_bf16.h>

#define NU 16384
#define NI 8192
#define TOPK 10
#define NTOT (NU + NI)   // 24576
#define OCAP 64

__device__ __forceinline__ float warp64_sum(float v) {
#pragma unroll
  for (int m = 32; m >= 1; m >>= 1) v += __shfl_xor(v, m);
  return v;
}

// proj = feat @ W + b ; xn = rownorm(proj). Tile: 32 rows x 64 cols (all cols), 256 thr.
__global__ __launch_bounds__(256) void proj_norm_kernel(
    const float* __restrict__ feat, const float* __restrict__ W,
    const float* __restrict__ b, float* __restrict__ xn, int D) {
  __shared__ float sA[64][32];   // [k][r]
  __shared__ float sB[64][68];   // [k][c], padded (68*4=272 keeps 16B align)
  const int tid = threadIdx.x;
  const int r0 = blockIdx.x * 32;
  const int rg = tid >> 4, cg = tid & 15;          // rows rg*2..+1, cols cg*4..+3
  const int rA = tid & 31, kbA = (tid >> 5) * 8;   // A-tile load mapping
  const int kB = tid & 63, cbB = (tid >> 6) * 16;  // B-tile load mapping
  float acc[2][4] = {{0, 0, 0, 0}, {0, 0, 0, 0}};
  for (int kc = 0; kc < D; kc += 64) {
    const float* fp = feat + (size_t)(r0 + rA) * D + kc + kbA;
    float4 p0 = *(const float4*)fp;
    float4 p1 = *(const float4*)(fp + 4);
    sA[kbA + 0][rA] = p0.x; sA[kbA + 1][rA] = p0.y;
    sA[kbA + 2][rA] = p0.z; sA[kbA + 3][rA] = p0.w;
    sA[kbA + 4][rA] = p1.x; sA[kbA + 5][rA] = p1.y;
    sA[kbA + 6][rA] = p1.z; sA[kbA + 7][rA] = p1.w;
    const float* wp = W + (size_t)(kc + kB) * 64 + cbB;
    float4 q0 = *(const float4*)(wp + 0);
    float4 q1 = *(const float4*)(wp + 4);
    float4 q2 = *(const float4*)(wp + 8);
    float4 q3 = *(const float4*)(wp + 12);
    *(float4*)&sB[kB][cbB + 0] = q0;
    *(float4*)&sB[kB][cbB + 4] = q1;
    *(float4*)&sB[kB][cbB + 8] = q2;
    *(float4*)&sB[kB][cbB + 12] = q3;
    __syncthreads();
#pragma unroll 8
    for (int k = 0; k < 64; ++k) {
      float2 a = *(const float2*)&sA[k][rg * 2];
      float4 bv = *(const float4*)&sB[k][cg * 4];
      acc[0][0] += a.x * bv.x; acc[0][1] += a.x * bv.y;
      acc[0][2] += a.x * bv.z; acc[0][3] += a.x * bv.w;
      acc[1][0] += a.y * bv.x; acc[1][1] += a.y * bv.y;
      acc[1][2] += a.y * bv.z; acc[1][3] += a.y * bv.w;
    }
    __syncthreads();
  }
  float4 bb = *(const float4*)(b + cg * 4);
#pragma unroll
  for (int rr = 0; rr < 2; ++rr) {
    float v0 = acc[rr][0] + bb.x, v1 = acc[rr][1] + bb.y;
    float v2 = acc[rr][2] + bb.z, v3 = acc[rr][3] + bb.w;
    float ss = v0 * v0 + v1 * v1 + v2 * v2 + v3 * v3;
#pragma unroll
    for (int m = 8; m >= 1; m >>= 1) ss += __shfl_xor(ss, m);  // 16-lane row group
    float inv = 1.0f / sqrtf(ss);
    float4 o = make_float4(v0 * inv, v1 * inv, v2 * inv, v3 * inv);
    *(float4*)(xn + (size_t)(r0 + rg * 2 + rr) * 64 + cg * 4) = o;
  }
}

// S = xn @ xn^T (8192x8192, K=64), exact top-10 per row (ties -> lower index).
__global__ __launch_bounds__(256) void sim_topk_kernel(
    const float* __restrict__ xn_v, const float* __restrict__ xn_t,
    float* __restrict__ tkv_v, int* __restrict__ tki_v,
    float* __restrict__ tkv_t, int* __restrict__ tki_t) {
  const float* xn = (blockIdx.y == 0) ? xn_v : xn_t;
  float* tkv = (blockIdx.y == 0) ? tkv_v : tkv_t;
  int* tki = (blockIdx.y == 0) ? tki_v : tki_t;
  __shared__ float sR[64][32];   // [k][r]
  __shared__ float sC[64][64];   // [k][c]
  const int tid = threadIdx.x;
  const int r0 = blockIdx.x * 32;
  const int rg = tid >> 4, cg = tid & 15;
  {
    int r = tid & 31, kb = (tid >> 5) * 8;
    const float* rp = xn + (size_t)(r0 + r) * 64 + kb;
    float4 p0 = *(const float4*)rp, p1 = *(const float4*)(rp + 4);
    sR[kb + 0][r] = p0.x; sR[kb + 1][r] = p0.y; sR[kb + 2][r] = p0.z; sR[kb + 3][r] = p0.w;
    sR[kb + 4][r] = p1.x; sR[kb + 5][r] = p1.y; sR[kb + 6][r] = p1.z; sR[kb + 7][r] = p1.w;
  }
  float av[2][TOPK];
  int ai[2][TOPK];
#pragma unroll
  for (int rr = 0; rr < 2; ++rr)
#pragma unroll
    for (int q = 0; q < TOPK; ++q) { av[rr][q] = -3.0e38f; ai[rr][q] = 0x7fffffff; }

  const int cl = tid & 63, kb2 = (tid >> 6) * 16;
  for (int c0 = 0; c0 < NI; c0 += 64) {
    __syncthreads();  // protect sC (and, first iter, publish sR)
    const float* cp = xn + (size_t)(c0 + cl) * 64 + kb2;
    float4 q0 = *(const float4*)(cp + 0), q1 = *(const float4*)(cp + 4);
    float4 q2 = *(const float4*)(cp + 8), q3 = *(const float4*)(cp + 12);
    sC[kb2 + 0][cl] = q0.x;  sC[kb2 + 1][cl] = q0.y;  sC[kb2 + 2][cl] = q0.z;  sC[kb2 + 3][cl] = q0.w;
    sC[kb2 + 4][cl] = q1.x;  sC[kb2 + 5][cl] = q1.y;  sC[kb2 + 6][cl] = q1.z;  sC[kb2 + 7][cl] = q1.w;
    sC[kb2 + 8][cl] = q2.x;  sC[kb2 + 9][cl] = q2.y;  sC[kb2 + 10][cl] = q2.z; sC[kb2 + 11][cl] = q2.w;
    sC[kb2 + 12][cl] = q3.x; sC[kb2 + 13][cl] = q3.y; sC[kb2 + 14][cl] = q3.z; sC[kb2 + 15][cl] = q3.w;
    __syncthreads();
    float acc[2][4] = {{0, 0, 0, 0}, {0, 0, 0, 0}};
#pragma unroll 8
    for (int k = 0; k < 64; ++k) {
      float2 a = *(const float2*)&sR[k][rg * 2];
      float4 bv = *(const float4*)&sC[k][cg * 4];
      acc[0][0] += a.x * bv.x; acc[0][1] += a.x * bv.y;
      acc[0][2] += a.x * bv.z; acc[0][3] += a.x * bv.w;
      acc[1][0] += a.y * bv.x; acc[1][1] += a.y * bv.y;
      acc[1][2] += a.y * bv.z; acc[1][3] += a.y * bv.w;
    }
#pragma unroll
    for (int rr = 0; rr < 2; ++rr) {
#pragma unroll
      for (int j = 0; j < 4; ++j) {
        float v = acc[rr][j];
        int c = c0 + cg * 4 + j;
        if (v > av[rr][TOPK - 1]) {  // branchless sorted insert (stable on ties)
          int cnt = 0;
#pragma unroll
          for (int q = 0; q < TOPK; ++q) cnt += (av[rr][q] >= v) ? 1 : 0;
#pragma unroll
          for (int q = TOPK - 1; q >= 0; --q) {
            int qm = (q > 0) ? q - 1 : 0;
            bool shift = (q > cnt);
            bool put = (q == cnt);
            float nv = shift ? av[rr][qm] : (put ? v : av[rr][q]);
            int ni = shift ? ai[rr][qm] : (put ? c : ai[rr][q]);
            av[rr][q] = nv; ai[rr][q] = ni;
          }
        }
      }
    }
  }
  // merge the 16 per-thread sorted lists of each row (16 contiguous lanes/group)
  const int gl = tid & 15;
#pragma unroll
  for (int rr = 0; rr < 2; ++rr) {
    int row = r0 + rg * 2 + rr;
    for (int q = 0; q < TOPK; ++q) {
      float v = av[rr][0];
      int c = ai[rr][0];
      int wl = gl;
#pragma unroll
      for (int m = 1; m < 16; m <<= 1) {
        float ov = __shfl_xor(v, m);
        int oc = __shfl_xor(c, m);
        int owl = __shfl_xor(wl, m);
        bool take = (ov > v) || (ov == v && oc < c);
        v = take ? ov : v; c = take ? oc : c; wl = take ? owl : wl;
      }
      if (gl == wl) {  // pop my head
#pragma unroll
        for (int t2 = 0; t2 < TOPK - 1; ++t2) { av[rr][t2] = av[rr][t2 + 1]; ai[rr][t2] = ai[rr][t2 + 1]; }
        av[rr][TOPK - 1] = -3.0e38f; ai[rr][TOPK - 1] = 0x7fffffff;
      }
      if (gl == 0) { tkv[(size_t)row * TOPK + q] = v; tki[(size_t)row * TOPK + q] = c; }
    }
  }
}

// dis[r] for normalized_laplacian(learned): d = w0*sum(topk_v)+w1*sum(topk_t)
__global__ void dis_kernel(const float* __restrict__ tkv_v, const float* __restrict__ tkv_t,
                           const float* __restrict__ iw, float* __restrict__ dis) {
  int r = blockIdx.x * blockDim.x + threadIdx.x;
  if (r >= NI) return;
  float ea = expf(iw[0]), eb = expf(iw[1]);
  float w0 = ea / (ea + eb), w1 = eb / (ea + eb);
  float s0 = 0.f, s1 = 0.f;
  for (int j = 0; j < TOPK; ++j) { s0 += tkv_v[r * TOPK + j]; s1 += tkv_t[r * TOPK + j]; }
  float d = w0 * s0 + w1 * s1;
  dis[r] = (d > 0.0f) ? (1.0f / sqrtf(d)) : 0.0f;
}

// stream Sim_v/Sim_t (10 nz/row) -> compact per-row lists with weight 0.7*w_m*val
__global__ __launch_bounds__(256) void scan_sim_kernel(
    const float* __restrict__ Sv, const float* __restrict__ St,
    const float* __restrict__ iw, int* __restrict__ ocols,
    float* __restrict__ ow, int* __restrict__ ocnt) {
  const int lane = threadIdx.x & 63;
  const int row = blockIdx.x * 4 + (threadIdx.x >> 6);
  float ea = expf(iw[0]), eb = expf(iw[1]);
  float wA = 0.7f * ea / (ea + eb), wB = 0.7f * eb / (ea + eb);
  int cnt = 0;
  int* oc = ocols + (size_t)row * OCAP;
  float* op = ow + (size_t)row * OCAP;
#pragma unroll 1
  for (int m = 0; m < 2; ++m) {
    const float* S = m ? St : Sv;
    float wgt = m ? wB : wA;
    const float4* rp = (const float4*)(S + (size_t)row * NI);
    for (int it = 0; it < NI / 256; ++it) {
      float4 v = rp[it * 64 + lane];
      int cb = it * 256 + lane * 4;
#pragma unroll
      for (int j = 0; j < 4; ++j) {
        float x = (j == 0) ? v.x : (j == 1) ? v.y : (j == 2) ? v.z : v.w;
        bool nz = (x != 0.0f);
        unsigned long long mk = __ballot(nz);
        int pre = __popcll(mk & ((1ull << lane) - 1ull));
        if (nz) {
          int p = cnt + pre;
          if (p < OCAP) { oc[p] = cb + j; op[p] = wgt * x; }
        }
        cnt += __popcll(mk);
      }
    }
  }
  if (lane == 0) ocnt[row] = (cnt < OCAP) ? cnt : OCAP;
}

// item_emb = Si @ Gi (sparse), then nitem = l2_normalize(item_emb)
__global__ __launch_bounds__(256) void item_emb_kernel(
    const float* __restrict__ Gi,
    const float* __restrict__ tkv_v, const int* __restrict__ tki_v,
    const float* __restrict__ tkv_t, const int* __restrict__ tki_t,
    const float* __restrict__ dis, const int* __restrict__ ocols,
    const float* __restrict__ ow, const int* __restrict__ ocnt,
    const float* __restrict__ iw, float* __restrict__ nitem) {
  const int d = threadIdx.x & 63;
  const int row = blockIdx.x * 4 + (threadIdx.x >> 6);
  float ea = expf(iw[0]), eb = expf(iw[1]);
  float w0 = ea / (ea + eb), w1 = eb / (ea + eb);
  float disr = dis[row];
  float acc = 0.0f;
#pragma unroll 1
  for (int m = 0; m < 2; ++m) {
    const float* tv = m ? tkv_t : tkv_v;
    const int* ti = m ? tki_t : tki_v;
    float wm = (m ? w1 : w0) * 0.3f * disr;
    for (int j = 0; j < TOPK; ++j) {
      float val = tv[(size_t)row * TOPK + j];
      int c = ti[(size_t)row * TOPK + j];
      acc += wm * val * dis[c] * Gi[(size_t)c * 64 + d];
    }
  }
  int cn = ocnt[row];
  for (int j = 0; j < cn; ++j) {
    int c = ocols[(size_t)row * OCAP + j];
    float wv = ow[(size_t)row * OCAP + j];
    acc += wv * Gi[(size_t)c * 64 + d];
  }
  float ss = warp64_sum(acc * acc);
  float nr = sqrtf(ss);
  nitem[(size_t)row * 64 + d] = acc / fmaxf(nr, 1e-12f);
}

__global__ void hist_kernel(const int* __restrict__ dst, int* __restrict__ deg, int n) {
  int e = blockIdx.x * blockDim.x + threadIdx.x;
  if (e < n) atomicAdd(&deg[dst[e]], 1);
}

__global__ __launch_bounds__(256) void scan_rowptr_kernel(
    const int* __restrict__ deg, int* __restrict__ row_ptr,
    int* __restrict__ cursor, int n) {
  __shared__ int s[256];
  __shared__ int carry;
  int tid = threadIdx.x;
  if (tid == 0) carry = 0;
  __syncthreads();
  for (int base = 0; base < n; base += 256) {
    int x = deg[base + tid];
    s[tid] = x;
    __syncthreads();
#pragma unroll
    for (int off = 1; off < 256; off <<= 1) {
      int t = (tid >= off) ? s[tid - off] : 0;
      __syncthreads();
      s[tid] += t;
      __syncthreads();
    }
    int incl = s[tid];
    int base_c = carry;
    int excl = base_c + incl - x;
    row_ptr[base + tid] = excl;
    cursor[base + tid] = excl;
    __syncthreads();
    if (tid == 255) carry = base_c + incl;
    __syncthreads();
  }
  if (tid == 0) row_ptr[n] = carry;
}

__global__ void fill_kernel(const int* __restrict__ src, const int* __restrict__ dst,
                            int* __restrict__ cursor, int* __restrict__ csr, int n) {
  int e = blockIdx.x * blockDim.x + threadIdx.x;
  if (e < n) {
    int p = atomicAdd(&cursor[dst[e]], 1);
    csr[p] = src[e];
  }
}

// agg[row] = sum over CSR sources; out = l2_normalize(agg)
__global__ __launch_bounds__(256) void segsum_kernel(
    const float* __restrict__ inU, const float* __restrict__ inI,
    const int* __restrict__ row_ptr, const int* __restrict__ csr,
    float* __restrict__ outp) {
  const int d = threadIdx.x & 63;
  const int row = blockIdx.x * 4 + (threadIdx.x >> 6);
  int a = row_ptr[row], bnd = row_ptr[row + 1];
  float acc = 0.0f;
  for (int e = a; e < bnd; ++e) {
    int s = csr[e];
    const float* sp = (s < NU) ? (inU + (size_t)s * 64) : (inI + (size_t)(s - NU) * 64);
    acc += sp[d];
  }
  float ss = warp64_sum(acc * acc);
  float nr = sqrtf(ss);
  outp[(size_t)row * 64 + d] = acc / fmaxf(nr, 1e-12f);
}

__global__ void final_kernel(const float* __restrict__ Gu, const float* __restrict__ Gi,
                             const float* __restrict__ e1b, const float* __restrict__ e2b,
                             const float* __restrict__ nitem, float* __restrict__ outp) {
  int idx = blockIdx.x * blockDim.x + threadIdx.x;
  int r = idx >> 6, d = idx & 63;
  float v0 = (r < NU) ? Gu[(size_t)r * 64 + d] : Gi[(size_t)(r - NU) * 64 + d];
  float v = (v0 + e1b[idx] + e2b[idx]) * (1.0f / 3.0f);
  if (r >= NU) v += nitem[(size_t)(r - NU) * 64 + d];
  outp[idx] = v;
}

extern "C" void kernel_launch(void* const* d_in, const int* in_sizes, int n_in,
                              void* d_out, int out_size, void* d_ws, size_t ws_size,
                              hipStream_t stream) {
  const float* Gu = (const float*)d_in[0];
  const float* Gi = (const float*)d_in[1];
  const float* feat_v = (const float*)d_in[2];
  const float* feat_t = (const float*)d_in[3];
  const float* W_v = (const float*)d_in[4];
  const float* b_v = (const float*)d_in[5];
  const float* W_t = (const float*)d_in[6];
  const float* b_t = (const float*)d_in[7];
  const float* iw = (const float*)d_in[8];
  const float* Sv = (const float*)d_in[9];
  const float* St = (const float*)d_in[10];
  const int* eidx = (const int*)d_in[11];
  const int twoE = in_sizes[11] / 2;  // 1048576 directed edges
  const int* esrc = eidx;
  const int* edst = eidx + twoE;
  float* outp = (float*)d_out;

  char* w = (char*)d_ws;
  size_t off = 0;
  auto alloc = [&](size_t bytes) -> void* {
    void* p = w + off;
    off = (off + bytes + 255) & ~(size_t)255;
    return p;
  };
  float* xn_v = (float*)alloc((size_t)NI * 64 * 4);
  float* xn_t = (float*)alloc((size_t)NI * 64 * 4);
  float* tkvV = (float*)alloc((size_t)NI * TOPK * 4);
  int* tkiV = (int*)alloc((size_t)NI * TOPK * 4);
  float* tkvT = (float*)alloc((size_t)NI * TOPK * 4);
  int* tkiT = (int*)alloc((size_t)NI * TOPK * 4);
  float* dis = (float*)alloc((size_t)NI * 4);
  int* ocols = (int*)alloc((size_t)NI * OCAP * 4);
  float* ow = (float*)alloc((size_t)NI * OCAP * 4);
  int* ocnt = (int*)alloc((size_t)NI * 4);
  float* nitem = (float*)alloc((size_t)NI * 64 * 4);
  float* e1b = (float*)alloc((size_t)NTOT * 64 * 4);
  float* e2b = (float*)alloc((size_t)NTOT * 64 * 4);
  int* deg = (int*)alloc((size_t)NTOT * 4);
  int* row_ptr = (int*)alloc((size_t)(NTOT + 1) * 4);
  int* cursor = (int*)alloc((size_t)NTOT * 4);
  int* csr = (int*)alloc((size_t)twoE * 4);
  if (off > ws_size) return;  // ws too small: fail visibly (output stays zero)

  hipMemsetAsync(deg, 0, (size_t)NTOT * 4, stream);

  proj_norm_kernel<<<NI / 32, 256, 0, stream>>>(feat_v, W_v, b_v, xn_v, 4096);
  proj_norm_kernel<<<NI / 32, 256, 0, stream>>>(feat_t, W_t, b_t, xn_t, 384);
  sim_topk_kernel<<<dim3(NI / 32, 2), 256, 0, stream>>>(xn_v, xn_t, tkvV, tkiV, tkvT, tkiT);
  dis_kernel<<<(NI + 255) / 256, 256, 0, stream>>>(tkvV, tkvT, iw, dis);
  scan_sim_kernel<<<NI / 4, 256, 0, stream>>>(Sv, St, iw, ocols, ow, ocnt);
  item_emb_kernel<<<NI / 4, 256, 0, stream>>>(Gi, tkvV, tkiV, tkvT, tkiT, dis, ocols, ow,
                                              ocnt, iw, nitem);
  hist_kernel<<<(twoE + 255) / 256, 256, 0, stream>>>(edst, deg, twoE);
  scan_rowptr_kernel<<<1, 256, 0, stream>>>(deg, row_ptr, cursor, NTOT);
  fill_kernel<<<(twoE + 255) / 256, 256, 0, stream>>>(esrc, edst, cursor, csr, twoE);
  segsum_kernel<<<NTOT / 4, 256, 0, stream>>>(Gu, Gi, row_ptr, csr, e1b);
  segsum_kernel<<<NTOT / 4, 256, 0, stream>>>(e1b, e1b + (size_t)NU * 64, row_ptr, csr, e2b);
  final_kernel<<<(NTOT * 64) / 256, 256, 0, stream>>>(Gu, Gi, e1b, e2b, nitem, outp);
}

// Round 3
// 1007.592 us; speedup vs baseline: 1.3723x; 1.3723x over previous
//
#include <hip/hip_runtime.h>
#include <hip/hip_bf16.h>

#define NU 16384
#define NI 8192
#define TOPK 10
#define NTOT (NU + NI)   // 24576
#define OCAP 64
#define NSEG 4
#define CSEG (NI / NSEG) // 2048
#define NCAND 16         // candidates per segment (ids only; rescored exactly)

typedef short short8v __attribute__((ext_vector_type(8)));
typedef float float4v __attribute__((ext_vector_type(4)));

__device__ __forceinline__ float warp64_sum(float v) {
#pragma unroll
  for (int m = 32; m >= 1; m >>= 1) v += __shfl_xor(v, m);
  return v;
}

// proj = feat @ W + b ; xn = rownorm(proj). Tile: 32 rows x 64 cols (all cols), 256 thr.
__global__ __launch_bounds__(256) void proj_norm_kernel(
    const float* __restrict__ feat, const float* __restrict__ W,
    const float* __restrict__ b, float* __restrict__ xn, int D) {
  __shared__ float sA[64][32];   // [k][r]
  __shared__ float sB[64][68];   // [k][c], padded
  const int tid = threadIdx.x;
  const int r0 = blockIdx.x * 32;
  const int rg = tid >> 4, cg = tid & 15;          // rows rg*2..+1, cols cg*4..+3
  const int rA = tid & 31, kbA = (tid >> 5) * 8;   // A-tile load mapping
  const int kB = tid & 63, cbB = (tid >> 6) * 16;  // B-tile load mapping
  float acc[2][4] = {{0, 0, 0, 0}, {0, 0, 0, 0}};
  for (int kc = 0; kc < D; kc += 64) {
    const float* fp = feat + (size_t)(r0 + rA) * D + kc + kbA;
    float4 p0 = *(const float4*)fp;
    float4 p1 = *(const float4*)(fp + 4);
    sA[kbA + 0][rA] = p0.x; sA[kbA + 1][rA] = p0.y;
    sA[kbA + 2][rA] = p0.z; sA[kbA + 3][rA] = p0.w;
    sA[kbA + 4][rA] = p1.x; sA[kbA + 5][rA] = p1.y;
    sA[kbA + 6][rA] = p1.z; sA[kbA + 7][rA] = p1.w;
    const float* wp = W + (size_t)(kc + kB) * 64 + cbB;
    float4 q0 = *(const float4*)(wp + 0);
    float4 q1 = *(const float4*)(wp + 4);
    float4 q2 = *(const float4*)(wp + 8);
    float4 q3 = *(const float4*)(wp + 12);
    *(float4*)&sB[kB][cbB + 0] = q0;
    *(float4*)&sB[kB][cbB + 4] = q1;
    *(float4*)&sB[kB][cbB + 8] = q2;
    *(float4*)&sB[kB][cbB + 12] = q3;
    __syncthreads();
#pragma unroll 8
    for (int k = 0; k < 64; ++k) {
      float2 a = *(const float2*)&sA[k][rg * 2];
      float4 bv = *(const float4*)&sB[k][cg * 4];
      acc[0][0] += a.x * bv.x; acc[0][1] += a.x * bv.y;
      acc[0][2] += a.x * bv.z; acc[0][3] += a.x * bv.w;
      acc[1][0] += a.y * bv.x; acc[1][1] += a.y * bv.y;
      acc[1][2] += a.y * bv.z; acc[1][3] += a.y * bv.w;
    }
    __syncthreads();
  }
  float4 bb = *(const float4*)(b + cg * 4);
#pragma unroll
  for (int rr = 0; rr < 2; ++rr) {
    float v0 = acc[rr][0] + bb.x, v1 = acc[rr][1] + bb.y;
    float v2 = acc[rr][2] + bb.z, v3 = acc[rr][3] + bb.w;
    float ss = v0 * v0 + v1 * v1 + v2 * v2 + v3 * v3;
#pragma unroll
    for (int m = 8; m >= 1; m >>= 1) ss += __shfl_xor(ss, m);  // 16-lane row group
    float inv = 1.0f / sqrtf(ss);
    float4 o = make_float4(v0 * inv, v1 * inv, v2 * inv, v3 * inv);
    *(float4*)(xn + (size_t)(r0 + rg * 2 + rr) * 64 + cg * 4) = o;
  }
}

// split f32 -> bf16 hi + bf16 lo (x ~= hi + lo), for 3-pass MFMA candidate gen
__global__ __launch_bounds__(256) void cvt_split_kernel(
    const float* __restrict__ xn, ushort* __restrict__ hi, ushort* __restrict__ lo) {
  int i = blockIdx.x * blockDim.x + threadIdx.x;
  float4 x = ((const float4*)xn)[i];
  ushort h[4], l[4];
  float xs[4] = {x.x, x.y, x.z, x.w};
#pragma unroll
  for (int j = 0; j < 4; ++j) {
    __hip_bfloat16 hb = __float2bfloat16(xs[j]);
    float hf = __bfloat162float(hb);
    __hip_bfloat16 lb = __float2bfloat16(xs[j] - hf);
    h[j] = *(ushort*)&hb;
    l[j] = *(ushort*)&lb;
  }
  ((ushort4*)hi)[i] = make_ushort4(h[0], h[1], h[2], h[3]);
  ((ushort4*)lo)[i] = make_ushort4(l[0], l[1], l[2], l[3]);
}

// S^T tiles via MFMA (bf16 hi/lo 3-pass), per-lane top-10, 4-lane merge -> 16 candidate ids.
// Block: 4 waves x 16 rows = 64 rows; cols = one segment of 2048, staged in LDS.
__global__ __launch_bounds__(256) void sim_topk_mfma_kernel(
    const ushort* __restrict__ hiV, const ushort* __restrict__ loV,
    const ushort* __restrict__ hiT, const ushort* __restrict__ loT,
    int* __restrict__ pki) {
  const int m = blockIdx.z;
  const ushort* hi = m ? hiT : hiV;
  const ushort* lo = m ? loT : loV;
  const int seg = blockIdx.y;
  const int c_base = seg * CSEG;
  const int r_base = blockIdx.x * 64;
  __shared__ ushort sH[64][64];
  __shared__ ushort sL[64][64];
  const int tid = threadIdx.x;
  const int wave = tid >> 6, lane = tid & 63;
  const int lr = lane & 15, lg = lane >> 4;
  const int my_row = r_base + wave * 16 + lr;
  // B fragments (this wave's 16 sim-rows), hi/lo x 2 K-chunks; col n = lane&15, k = lg*8+e
  short8v bh[2], bl[2];
  {
    const ushort* rp = hi + (size_t)my_row * 64 + lg * 8;
    bh[0] = *(const short8v*)(rp);
    bh[1] = *(const short8v*)(rp + 32);
    const ushort* rp2 = lo + (size_t)my_row * 64 + lg * 8;
    bl[0] = *(const short8v*)(rp2);
    bl[1] = *(const short8v*)(rp2 + 32);
  }
  float av[TOPK];
  int ai[TOPK];
#pragma unroll
  for (int q = 0; q < TOPK; ++q) { av[q] = -3.0e38f; ai[q] = 0x7fffffff; }

  // staging map: thread t -> col-row sc = t>>2, 32B chunk sq = (t&3)*32 (row = 128B)
  const int sc = tid >> 2, sq = (tid & 3) * 32;
  const int sw = (sc & 7) << 4;  // XOR swizzle (G4)
  for (int c0 = 0; c0 < CSEG; c0 += 64) {
    __syncthreads();
    const char* gh = (const char*)(hi + (size_t)(c_base + c0 + sc) * 64);
    const char* gl2 = (const char*)(lo + (size_t)(c_base + c0 + sc) * 64);
    *(float4*)((char*)&sH[sc][0] + (sq ^ sw)) = *(const float4*)(gh + sq);
    *(float4*)((char*)&sH[sc][0] + ((sq + 16) ^ sw)) = *(const float4*)(gh + sq + 16);
    *(float4*)((char*)&sL[sc][0] + (sq ^ sw)) = *(const float4*)(gl2 + sq);
    *(float4*)((char*)&sL[sc][0] + ((sq + 16) ^ sw)) = *(const float4*)(gl2 + sq + 16);
    __syncthreads();
#pragma unroll
    for (int s = 0; s < 4; ++s) {
      const int ca = s * 16 + lr;          // A-row = local col index
      const int cw = (ca & 7) << 4;
      const int kb0 = (lg * 16) ^ cw;      // K-chunk 0 byte offset
      const int kb1 = (lg * 16 + 64) ^ cw; // K-chunk 1
      short8v ah0 = *(const short8v*)((const char*)&sH[ca][0] + kb0);
      short8v ah1 = *(const short8v*)((const char*)&sH[ca][0] + kb1);
      short8v al0 = *(const short8v*)((const char*)&sL[ca][0] + kb0);
      short8v al1 = *(const short8v*)((const char*)&sL[ca][0] + kb1);
      float4v acc = {0.f, 0.f, 0.f, 0.f};
      acc = __builtin_amdgcn_mfma_f32_16x16x32_bf16(ah0, bh[0], acc, 0, 0, 0);
      acc = __builtin_amdgcn_mfma_f32_16x16x32_bf16(ah1, bh[1], acc, 0, 0, 0);
      acc = __builtin_amdgcn_mfma_f32_16x16x32_bf16(ah0, bl[0], acc, 0, 0, 0);
      acc = __builtin_amdgcn_mfma_f32_16x16x32_bf16(ah1, bl[1], acc, 0, 0, 0);
      acc = __builtin_amdgcn_mfma_f32_16x16x32_bf16(al0, bh[0], acc, 0, 0, 0);
      acc = __builtin_amdgcn_mfma_f32_16x16x32_bf16(al1, bh[1], acc, 0, 0, 0);
#pragma unroll
      for (int j = 0; j < 4; ++j) {
        float v = acc[j];
        int c = c_base + c0 + s * 16 + lg * 4 + j;
        if (v > av[TOPK - 1]) {  // branchless sorted insert
          int cnt = 0;
#pragma unroll
          for (int q = 0; q < TOPK; ++q) cnt += (av[q] >= v) ? 1 : 0;
#pragma unroll
          for (int q = TOPK - 1; q >= 0; --q) {
            int qm = (q > 0) ? q - 1 : 0;
            bool shift = (q > cnt);
            bool put = (q == cnt);
            float nv = shift ? av[qm] : (put ? v : av[q]);
            int ni = shift ? ai[qm] : (put ? c : ai[q]);
            av[q] = nv; ai[q] = ni;
          }
        }
      }
    }
  }
  // merge 4 lanes holding the same sim-row (xor 16, 32); pop 16 candidates, ids only
  const size_t obase = ((size_t)(m * NSEG + seg) * NI + my_row) * NCAND;
  for (int q = 0; q < NCAND; ++q) {
    float v = av[0];
    int c = ai[0];
    int wl = lane;
#pragma unroll
    for (int mm = 16; mm <= 32; mm <<= 1) {
      float ov = __shfl_xor(v, mm);
      int oc = __shfl_xor(c, mm);
      int owl = __shfl_xor(wl, mm);
      bool take = (ov > v) || (ov == v && oc < c);
      v = take ? ov : v; c = take ? oc : c; wl = take ? owl : wl;
    }
    if (wl == lane) {  // pop my head
#pragma unroll
      for (int t2 = 0; t2 < TOPK - 1; ++t2) { av[t2] = av[t2 + 1]; ai[t2] = ai[t2 + 1]; }
      av[TOPK - 1] = -3.0e38f; ai[TOPK - 1] = 0x7fffffff;
    }
    if (lg == 0) pki[obase + q] = c;
  }
}

// exact f32 rescoring of 4x16 candidates per (modality,row) + exact top-10 (tie: lower idx)
__global__ __launch_bounds__(256) void rescore_kernel(
    const float* __restrict__ xn_v, const float* __restrict__ xn_t,
    const int* __restrict__ pki,
    float* __restrict__ tkvV, int* __restrict__ tkiV,
    float* __restrict__ tkvT, int* __restrict__ tkiT) {
  const int task = blockIdx.x * 4 + (threadIdx.x >> 6);  // 0 .. 2*NI-1
  const int lane = threadIdx.x & 63;
  const int m = task >> 13;       // task / NI
  const int row = task & (NI - 1);
  const float* xn = m ? xn_t : xn_v;
  const int seg = lane >> 4, q = lane & 15;
  int c = pki[(((size_t)(m * NSEG + seg)) * NI + row) * NCAND + q];
  const bool valid = ((unsigned)c < (unsigned)NI);
  const float4* rp = (const float4*)(xn + (size_t)row * 64);
  const float4* cp = (const float4*)(xn + (size_t)(valid ? c : 0) * 64);
  float s = 0.0f;
#pragma unroll
  for (int k = 0; k < 16; ++k) {
    float4 a = rp[k];
    float4 bv = cp[k];
    s += a.x * bv.x; s += a.y * bv.y; s += a.z * bv.z; s += a.w * bv.w;
  }
  float v = valid ? s : -3.0e38f;
  int cc = valid ? c : 0x7fffffff;
  float* tv = m ? tkvT : tkvV;
  int* ti = m ? tkiT : tkiV;
  for (int t = 0; t < TOPK; ++t) {
    float bv2 = v; int bc = cc; int wl = lane;
#pragma unroll
    for (int mm = 1; mm < 64; mm <<= 1) {
      float ov = __shfl_xor(bv2, mm);
      int oc = __shfl_xor(bc, mm);
      int owl = __shfl_xor(wl, mm);
      bool take = (ov > bv2) || (ov == bv2 && oc < bc);
      bv2 = take ? ov : bv2; bc = take ? oc : bc; wl = take ? owl : wl;
    }
    if (lane == wl) { v = -3.0e38f; cc = 0x7fffffff; }  // winner removes itself
    if (lane == 0) { tv[(size_t)row * TOPK + t] = bv2; ti[(size_t)row * TOPK + t] = bc; }
  }
}

// dis[r] for normalized_laplacian(learned): d = w0*sum(topk_v)+w1*sum(topk_t)
__global__ void dis_kernel(const float* __restrict__ tkv_v, const float* __restrict__ tkv_t,
                           const float* __restrict__ iw, float* __restrict__ dis) {
  int r = blockIdx.x * blockDim.x + threadIdx.x;
  if (r >= NI) return;
  float ea = expf(iw[0]), eb = expf(iw[1]);
  float w0 = ea / (ea + eb), w1 = eb / (ea + eb);
  float s0 = 0.f, s1 = 0.f;
  for (int j = 0; j < TOPK; ++j) { s0 += tkv_v[r * TOPK + j]; s1 += tkv_t[r * TOPK + j]; }
  float d = w0 * s0 + w1 * s1;
  dis[r] = (d > 0.0f) ? (1.0f / sqrtf(d)) : 0.0f;
}

// stream Sim_v/Sim_t (10 nz/row) -> compact per-row lists with weight 0.7*w_m*val
__global__ __launch_bounds__(256) void scan_sim_kernel(
    const float* __restrict__ Sv, const float* __restrict__ St,
    const float* __restrict__ iw, int* __restrict__ ocols,
    float* __restrict__ ow, int* __restrict__ ocnt) {
  const int lane = threadIdx.x & 63;
  const int row = blockIdx.x * 4 + (threadIdx.x >> 6);
  float ea = expf(iw[0]), eb = expf(iw[1]);
  float wA = 0.7f * ea / (ea + eb), wB = 0.7f * eb / (ea + eb);
  int cnt = 0;
  int* oc = ocols + (size_t)row * OCAP;
  float* op = ow + (size_t)row * OCAP;
#pragma unroll 1
  for (int m = 0; m < 2; ++m) {
    const float* S = m ? St : Sv;
    float wgt = m ? wB : wA;
    const float4* rp = (const float4*)(S + (size_t)row * NI);
    for (int it = 0; it < NI / 256; ++it) {
      float4 v = rp[it * 64 + lane];
      int cb = it * 256 + lane * 4;
#pragma unroll
      for (int j = 0; j < 4; ++j) {
        float x = (j == 0) ? v.x : (j == 1) ? v.y : (j == 2) ? v.z : v.w;
        bool nz = (x != 0.0f);
        unsigned long long mk = __ballot(nz);
        int pre = __popcll(mk & ((1ull << lane) - 1ull));
        if (nz) {
          int p = cnt + pre;
          if (p < OCAP) { oc[p] = cb + j; op[p] = wgt * x; }
        }
        cnt += __popcll(mk);
      }
    }
  }
  if (lane == 0) ocnt[row] = (cnt < OCAP) ? cnt : OCAP;
}

// item_emb = Si @ Gi (sparse), then nitem = l2_normalize(item_emb)
__global__ __launch_bounds__(256) void item_emb_kernel(
    const float* __restrict__ Gi,
    const float* __restrict__ tkv_v, const int* __restrict__ tki_v,
    const float* __restrict__ tkv_t, const int* __restrict__ tki_t,
    const float* __restrict__ dis, const int* __restrict__ ocols,
    const float* __restrict__ ow, const int* __restrict__ ocnt,
    const float* __restrict__ iw, float* __restrict__ nitem) {
  const int d = threadIdx.x & 63;
  const int row = blockIdx.x * 4 + (threadIdx.x >> 6);
  float ea = expf(iw[0]), eb = expf(iw[1]);
  float w0 = ea / (ea + eb), w1 = eb / (ea + eb);
  float disr = dis[row];
  float acc = 0.0f;
#pragma unroll 1
  for (int m = 0; m < 2; ++m) {
    const float* tv = m ? tkv_t : tkv_v;
    const int* ti = m ? tki_t : tki_v;
    float wm = (m ? w1 : w0) * 0.3f * disr;
    for (int j = 0; j < TOPK; ++j) {
      float val = tv[(size_t)row * TOPK + j];
      int c = ti[(size_t)row * TOPK + j];
      acc += wm * val * dis[c] * Gi[(size_t)c * 64 + d];
    }
  }
  int cn = ocnt[row];
  for (int j = 0; j < cn; ++j) {
    int c = ocols[(size_t)row * OCAP + j];
    float wv = ow[(size_t)row * OCAP + j];
    acc += wv * Gi[(size_t)c * 64 + d];
  }
  float ss = warp64_sum(acc * acc);
  float nr = sqrtf(ss);
  nitem[(size_t)row * 64 + d] = acc / fmaxf(nr, 1e-12f);
}

__global__ void hist_kernel(const int* __restrict__ dst, int* __restrict__ deg, int n) {
  int e = blockIdx.x * blockDim.x + threadIdx.x;
  if (e < n) atomicAdd(&deg[dst[e]], 1);
}

__global__ __launch_bounds__(256) void scan_rowptr_kernel(
    const int* __restrict__ deg, int* __restrict__ row_ptr,
    int* __restrict__ cursor, int n) {
  __shared__ int s[256];
  __shared__ int carry;
  int tid = threadIdx.x;
  if (tid == 0) carry = 0;
  __syncthreads();
  for (int base = 0; base < n; base += 256) {
    int x = deg[base + tid];
    s[tid] = x;
    __syncthreads();
#pragma unroll
    for (int off = 1; off < 256; off <<= 1) {
      int t = (tid >= off) ? s[tid - off] : 0;
      __syncthreads();
      s[tid] += t;
      __syncthreads();
    }
    int incl = s[tid];
    int base_c = carry;
    int excl = base_c + incl - x;
    row_ptr[base + tid] = excl;
    cursor[base + tid] = excl;
    __syncthreads();
    if (tid == 255) carry = base_c + incl;
    __syncthreads();
  }
  if (tid == 0) row_ptr[n] = carry;
}

__global__ void fill_kernel(const int* __restrict__ src, const int* __restrict__ dst,
                            int* __restrict__ cursor, int* __restrict__ csr, int n) {
  int e = blockIdx.x * blockDim.x + threadIdx.x;
  if (e < n) {
    int p = atomicAdd(&cursor[dst[e]], 1);
    csr[p] = src[e];
  }
}

// agg[row] = sum over CSR sources; out = l2_normalize(agg)
__global__ __launch_bounds__(256) void segsum_kernel(
    const float* __restrict__ inU, const float* __restrict__ inI,
    const int* __restrict__ row_ptr, const int* __restrict__ csr,
    float* __restrict__ outp) {
  const int d = threadIdx.x & 63;
  const int row = blockIdx.x * 4 + (threadIdx.x >> 6);
  int a = row_ptr[row], bnd = row_ptr[row + 1];
  float acc = 0.0f;
  for (int e = a; e < bnd; ++e) {
    int s = csr[e];
    const float* sp = (s < NU) ? (inU + (size_t)s * 64) : (inI + (size_t)(s - NU) * 64);
    acc += sp[d];
  }
  float ss = warp64_sum(acc * acc);
  float nr = sqrtf(ss);
  outp[(size_t)row * 64 + d] = acc / fmaxf(nr, 1e-12f);
}

__global__ void final_kernel(const float* __restrict__ Gu, const float* __restrict__ Gi,
                             const float* __restrict__ e1b, const float* __restrict__ e2b,
                             const float* __restrict__ nitem, float* __restrict__ outp) {
  int idx = blockIdx.x * blockDim.x + threadIdx.x;
  int r = idx >> 6, d = idx & 63;
  float v0 = (r < NU) ? Gu[(size_t)r * 64 + d] : Gi[(size_t)(r - NU) * 64 + d];
  float v = (v0 + e1b[idx] + e2b[idx]) * (1.0f / 3.0f);
  if (r >= NU) v += nitem[(size_t)(r - NU) * 64 + d];
  outp[idx] = v;
}

extern "C" void kernel_launch(void* const* d_in, const int* in_sizes, int n_in,
                              void* d_out, int out_size, void* d_ws, size_t ws_size,
                              hipStream_t stream) {
  const float* Gu = (const float*)d_in[0];
  const float* Gi = (const float*)d_in[1];
  const float* feat_v = (const float*)d_in[2];
  const float* feat_t = (const float*)d_in[3];
  const float* W_v = (const float*)d_in[4];
  const float* b_v = (const float*)d_in[5];
  const float* W_t = (const float*)d_in[6];
  const float* b_t = (const float*)d_in[7];
  const float* iw = (const float*)d_in[8];
  const float* Sv = (const float*)d_in[9];
  const float* St = (const float*)d_in[10];
  const int* eidx = (const int*)d_in[11];
  const int twoE = in_sizes[11] / 2;  // 1048576 directed edges
  const int* esrc = eidx;
  const int* edst = eidx + twoE;
  float* outp = (float*)d_out;

  char* w = (char*)d_ws;
  size_t off = 0;
  auto alloc = [&](size_t bytes) -> void* {
    void* p = w + off;
    off = (off + bytes + 255) & ~(size_t)255;
    return p;
  };
  float* xn_v = (float*)alloc((size_t)NI * 64 * 4);
  float* xn_t = (float*)alloc((size_t)NI * 64 * 4);
  ushort* hiV = (ushort*)alloc((size_t)NI * 64 * 2);
  ushort* loV = (ushort*)alloc((size_t)NI * 64 * 2);
  ushort* hiT = (ushort*)alloc((size_t)NI * 64 * 2);
  ushort* loT = (ushort*)alloc((size_t)NI * 64 * 2);
  int* pki = (int*)alloc((size_t)2 * NSEG * NI * NCAND * 4);
  float* tkvV = (float*)alloc((size_t)NI * TOPK * 4);
  int* tkiV = (int*)alloc((size_t)NI * TOPK * 4);
  float* tkvT = (float*)alloc((size_t)NI * TOPK * 4);
  int* tkiT = (int*)alloc((size_t)NI * TOPK * 4);
  float* dis = (float*)alloc((size_t)NI * 4);
  int* ocols = (int*)alloc((size_t)NI * OCAP * 4);
  float* ow = (float*)alloc((size_t)NI * OCAP * 4);
  int* ocnt = (int*)alloc((size_t)NI * 4);
  float* nitem = (float*)alloc((size_t)NI * 64 * 4);
  float* e1b = (float*)alloc((size_t)NTOT * 64 * 4);
  float* e2b = (float*)alloc((size_t)NTOT * 64 * 4);
  int* deg = (int*)alloc((size_t)NTOT * 4);
  int* row_ptr = (int*)alloc((size_t)(NTOT + 1) * 4);
  int* cursor = (int*)alloc((size_t)NTOT * 4);
  int* csr = (int*)alloc((size_t)twoE * 4);
  if (off > ws_size) return;  // ws too small: fail visibly (output stays zero)

  hipMemsetAsync(deg, 0, (size_t)NTOT * 4, stream);

  proj_norm_kernel<<<NI / 32, 256, 0, stream>>>(feat_v, W_v, b_v, xn_v, 4096);
  proj_norm_kernel<<<NI / 32, 256, 0, stream>>>(feat_t, W_t, b_t, xn_t, 384);
  cvt_split_kernel<<<(NI * 64 / 4) / 256, 256, 0, stream>>>(xn_v, hiV, loV);
  cvt_split_kernel<<<(NI * 64 / 4) / 256, 256, 0, stream>>>(xn_t, hiT, loT);
  sim_topk_mfma_kernel<<<dim3(NI / 64, NSEG, 2), 256, 0, stream>>>(hiV, loV, hiT, loT, pki);
  rescore_kernel<<<(2 * NI) / 4, 256, 0, stream>>>(xn_v, xn_t, pki, tkvV, tkiV, tkvT, tkiT);
  dis_kernel<<<(NI + 255) / 256, 256, 0, stream>>>(tkvV, tkvT, iw, dis);
  scan_sim_kernel<<<NI / 4, 256, 0, stream>>>(Sv, St, iw, ocols, ow, ocnt);
  item_emb_kernel<<<NI / 4, 256, 0, stream>>>(Gi, tkvV, tkiV, tkvT, tkiT, dis, ocols, ow,
                                              ocnt, iw, nitem);
  hist_kernel<<<(twoE + 255) / 256, 256, 0, stream>>>(edst, deg, twoE);
  scan_rowptr_kernel<<<1, 256, 0, stream>>>(deg, row_ptr, cursor, NTOT);
  fill_kernel<<<(twoE + 255) / 256, 256, 0, stream>>>(esrc, edst, cursor, csr, twoE);
  segsum_kernel<<<NTOT / 4, 256, 0, stream>>>(Gu, Gi, row_ptr, csr, e1b);
  segsum_kernel<<<NTOT / 4, 256, 0, stream>>>(e1b, e1b + (size_t)NU * 64, row_ptr, csr, e2b);
  final_kernel<<<(NTOT * 64) / 256, 256, 0, stream>>>(Gu, Gi, e1b, e2b, nitem, outp);
}